// Round 2
// baseline (34936.227 us; speedup 1.0000x reference)
//
#include <hip/hip_runtime.h>
#include <stdint.h>

// ---------------------------------------------------------------------------
// BidirectionalGRU: rmsnorm -> 2-layer bidirectional GRU -> out-proj residual
//                   -> rmsnorm -> SwiGLU FFN residual.
// B=8, S=1024, DIM=1024, FFN_HID=2816.
// External dtype (fp32 vs bf16) detected at runtime from gru_norm_w (all-ones):
// first u32 == 0x3F800000 iff fp32. Internal compute/storage is bf16 + fp32 acc.
// ---------------------------------------------------------------------------

#define S_LEN 1024
#define NWG_DIR 64     // workgroups per GRU direction
#define HPW 16         // hidden units per workgroup
#define WSTR 1032      // LDS row stride (elems) for weight/h tiles (pad 8)

typedef __attribute__((ext_vector_type(8))) __bf16 bf16x8;
typedef __attribute__((ext_vector_type(4))) float f32x4;

__device__ __forceinline__ float bf2f(unsigned short u) {
    union { unsigned int i; float f; } v; v.i = ((unsigned int)u) << 16; return v.f;
}
__device__ __forceinline__ unsigned short f2bf(float f) {
    unsigned int i = __float_as_uint(f);
    unsigned int r = (i + 0x7fffu + ((i >> 16) & 1u)) >> 16;   // RNE
    return (unsigned short)r;
}
__device__ __forceinline__ bool dt_is_f32(const unsigned int* dt) {
    return dt[0] == 0x3F800000u;
}
__device__ __forceinline__ float ld_ext(const void* p, long i, bool f32) {
    return f32 ? ((const float*)p)[i] : bf2f(((const unsigned short*)p)[i]);
}
__device__ __forceinline__ void st8bf(unsigned short* d, float4 a, float4 b) {
    uint4 u;
    u.x = (unsigned)f2bf(a.x) | ((unsigned)f2bf(a.y) << 16);
    u.y = (unsigned)f2bf(a.z) | ((unsigned)f2bf(a.w) << 16);
    u.z = (unsigned)f2bf(b.x) | ((unsigned)f2bf(b.y) << 16);
    u.w = (unsigned)f2bf(b.z) | ((unsigned)f2bf(b.w) << 16);
    *(uint4*)d = u;
}
__device__ __forceinline__ void gload_lds16(const void* g, void* l) {
    __builtin_amdgcn_global_load_lds(
        (const __attribute__((address_space(1))) unsigned int*)g,
        (__attribute__((address_space(3))) unsigned int*)l, 16, 0, 0);
}

// ---------------------------------------------------------------------------
// RMSNorm over 1024-elem rows. EXT_IN: x is an external input (flag dtype);
// otherwise x is the internal fp32 buffer. Output always internal bf16.
// ---------------------------------------------------------------------------
template <bool EXT_IN>
__global__ __launch_bounds__(256) void rmsnorm_k(const void* __restrict__ xin,
                                                 const void* __restrict__ w,
                                                 unsigned short* __restrict__ outp,
                                                 const unsigned int* __restrict__ dt) {
    const bool f32 = dt_is_f32(dt);
    const long row = blockIdx.x;
    const int tid = threadIdx.x;
    float v[4];
    if (!EXT_IN || f32) {
        const float* x = (const float*)xin + row * 1024 + tid * 4;
        f32x4 f = *(const f32x4*)x;
        v[0] = f[0]; v[1] = f[1]; v[2] = f[2]; v[3] = f[3];
    } else {
        const unsigned short* x = (const unsigned short*)xin + row * 1024 + tid * 4;
        uint2 u = *(const uint2*)x;
        v[0] = bf2f((unsigned short)(u.x & 0xffff)); v[1] = bf2f((unsigned short)(u.x >> 16));
        v[2] = bf2f((unsigned short)(u.y & 0xffff)); v[3] = bf2f((unsigned short)(u.y >> 16));
    }
    float ss = v[0]*v[0] + v[1]*v[1] + v[2]*v[2] + v[3]*v[3];
    for (int off = 32; off > 0; off >>= 1) ss += __shfl_down(ss, off, 64);
    __shared__ float red[4];
    __shared__ float bc;
    if ((tid & 63) == 0) red[tid >> 6] = ss;
    __syncthreads();
    if (tid == 0) bc = rsqrtf((red[0] + red[1] + red[2] + red[3]) * (1.f / 1024.f) + 1e-5f);
    __syncthreads();
    const float sc = bc;
    unsigned short o0 = f2bf(v[0] * sc * ld_ext(w, tid*4+0, f32));
    unsigned short o1 = f2bf(v[1] * sc * ld_ext(w, tid*4+1, f32));
    unsigned short o2 = f2bf(v[2] * sc * ld_ext(w, tid*4+2, f32));
    unsigned short o3 = f2bf(v[3] * sc * ld_ext(w, tid*4+3, f32));
    *(uint2*)(outp + row * 1024 + tid * 4) =
        make_uint2((unsigned int)o0 | ((unsigned int)o1 << 16),
                   (unsigned int)o2 | ((unsigned int)o3 << 16));
}

// ---------------------------------------------------------------------------
// GEMM: C[M,N] = A[M,K] @ W[N,K]^T (+bias) (+epilogue). A internal bf16;
// W/bias external (flag dtype). 128x128 tile, BK=32, 2x2 waves, 16x16x32 MFMA.
// ---------------------------------------------------------------------------
enum { EPI_NONE = 0, EPI_SILU = 1, EPI_MUL_I = 2, EPI_ADD_EXT = 3, EPI_ADD_F32 = 4 };
enum { OUT_BF16 = 0, OUT_F32 = 1, OUT_EXT = 2 };

template <int EPI, int OUTMODE, bool HAS_BIAS>
__global__ __launch_bounds__(256) void gemm_bt(const unsigned short* __restrict__ A,
                                               const void* __restrict__ W,
                                               const void* __restrict__ bias,
                                               const void* __restrict__ aux,
                                               void* __restrict__ Cout, int N, int K,
                                               const unsigned int* __restrict__ dt) {
    __shared__ __align__(16) unsigned short sA[128 * 32];
    __shared__ __align__(16) unsigned short sB[128 * 32];
    const bool f32 = dt_is_f32(dt);
    const int tid = threadIdx.x;
    const int lane = tid & 63;
    const int wave = tid >> 6;
    const int wm = (wave >> 1) * 64, wn = (wave & 1) * 64;
    const int lm = lane & 15, q = lane >> 4;
    const long rowA0 = (long)blockIdx.y * 128;
    const long rowB0 = (long)blockIdx.x * 128;
    const int r0 = tid >> 2, c0 = tid & 3;

    f32x4 acc[4][4] = {};

    for (int kt = 0; kt < K; kt += 32) {
        gload_lds16(A + (rowA0 + r0) * K + kt + c0 * 8, &sA[tid * 8]);
        gload_lds16(A + (rowA0 + r0 + 64) * K + kt + c0 * 8, &sA[(tid + 256) * 8]);
        if (!f32) {
            const unsigned short* Wb = (const unsigned short*)W;
            gload_lds16(Wb + (rowB0 + r0) * K + kt + c0 * 8, &sB[tid * 8]);
            gload_lds16(Wb + (rowB0 + r0 + 64) * K + kt + c0 * 8, &sB[(tid + 256) * 8]);
        } else {
            const float* Wf = (const float*)W;
            const float* p0 = Wf + (rowB0 + r0) * K + kt + c0 * 8;
            const float* p1 = Wf + (rowB0 + r0 + 64) * K + kt + c0 * 8;
            float4 a0 = *(const float4*)p0, a1 = *(const float4*)(p0 + 4);
            float4 b0 = *(const float4*)p1, b1 = *(const float4*)(p1 + 4);
            st8bf(&sB[tid * 8], a0, a1);
            st8bf(&sB[(tid + 256) * 8], b0, b1);
        }
        __syncthreads();
        bf16x8 af[4], bfr[4];
#pragma unroll
        for (int i = 0; i < 4; ++i) af[i] = *(const bf16x8*)&sA[(wm + i * 16 + lm) * 32 + q * 8];
#pragma unroll
        for (int j = 0; j < 4; ++j) bfr[j] = *(const bf16x8*)&sB[(wn + j * 16 + lm) * 32 + q * 8];
#pragma unroll
        for (int i = 0; i < 4; ++i)
#pragma unroll
            for (int j = 0; j < 4; ++j)
                acc[i][j] = __builtin_amdgcn_mfma_f32_16x16x32_bf16(af[i], bfr[j], acc[i][j], 0, 0, 0);
        __syncthreads();
    }

#pragma unroll
    for (int j = 0; j < 4; ++j) {
        const long col = rowB0 + wn + j * 16 + lm;
        float bv = 0.f;
        if (HAS_BIAS) bv = ld_ext(bias, col, f32);
#pragma unroll
        for (int i = 0; i < 4; ++i) {
#pragma unroll
            for (int r = 0; r < 4; ++r) {
                const long row = rowA0 + wm + i * 16 + q * 4 + r;
                const long idx = row * N + col;
                float v = acc[i][j][r] + bv;
                if (EPI == EPI_SILU)    v = v / (1.f + __expf(-v));
                if (EPI == EPI_MUL_I)   v *= bf2f(((const unsigned short*)aux)[idx]);
                if (EPI == EPI_ADD_EXT) v += ld_ext(aux, idx, f32);
                if (EPI == EPI_ADD_F32) v += ((const float*)aux)[idx];
                if (OUTMODE == OUT_F32)       ((float*)Cout)[idx] = v;
                else if (OUTMODE == OUT_BF16) ((unsigned short*)Cout)[idx] = f2bf(v);
                else { if (f32) ((float*)Cout)[idx] = v; else ((unsigned short*)Cout)[idx] = f2bf(v); }
            }
        }
    }
}

// ---------------------------------------------------------------------------
// GRU recurrence (one bidirectional layer). Grid = 128 wgs x 256 thr.
// wg (dir, slot): owns hidden units [slot*16, slot*16+16). w_hh slice (48 rows
// of 1024) LDS-resident for all 1024 steps. Per step: stage h_{t-1} (bf16,
// ping-pong global), MFMA K-split across 4 waves, LDS reduce, gate math on
// 128 threads (fp32 carried state), publish h_t + release-count; consumers
// acquire-spin. xg for step t+1 prefetched during step t.
// ---------------------------------------------------------------------------
__global__ __launch_bounds__(256) void gru_recur(const unsigned short* __restrict__ xg,  // [8192][6144]
                                                 const void* __restrict__ whh,           // [2][3072][1024]
                                                 const void* __restrict__ bhh,           // [2][3072]
                                                 unsigned short* __restrict__ out,       // [8192][2048]
                                                 unsigned short* __restrict__ hpp,       // [2][2][8][1024]
                                                 unsigned int* __restrict__ cnt,         // [2]
                                                 const unsigned int* __restrict__ dt) {
    extern __shared__ char smem[];
    unsigned short* w_lds = (unsigned short*)smem;            // 48*1032
    unsigned short* h_lds = w_lds + 48 * WSTR;                // 16*1032 (rows 8..15 stay zero)
    float* xg_lds = (float*)(h_lds + 16 * WSTR);              // [2][8][48]
    float* red = xg_lds + 768;                                // [4][3][64][4]
    float* hstate = red + 3072;                               // [8][16] fp32 carried state
    float* bhh_l = hstate + 128;                              // [48]

    const bool f32 = dt_is_f32(dt);
    const int tid = threadIdx.x;
    const int lane = tid & 63, wave = tid >> 6;
    const int dir = blockIdx.x >> 6;
    const int H0 = (blockIdx.x & 63) * HPW;
    const int lm = lane & 15, q = lane >> 4;

    // ---- one-time init ----
    for (int idx = tid; idx < 48 * 128; idx += 256) {
        int row = idx >> 7, seg = idx & 127;
        int gate = row >> 4, j = row & 15;
        size_t grow = (size_t)(dir * 3072 + gate * 1024 + H0 + j);
        if (!f32) {
            uint4 vv = *(const uint4*)((const unsigned short*)whh + grow * 1024 + seg * 8);
            *(uint4*)&w_lds[row * WSTR + seg * 8] = vv;
        } else {
            const float* wf = (const float*)whh + grow * 1024 + seg * 8;
            float4 a = *(const float4*)wf, b = *(const float4*)(wf + 4);
            st8bf(&w_lds[row * WSTR + seg * 8], a, b);
        }
    }
    if (tid < 48) {
        int gate = tid >> 4, j = tid & 15;
        bhh_l[tid] = ld_ext(bhh, dir * 3072 + gate * 1024 + H0 + j, f32);
    }
    if (tid < 128) hstate[tid] = 0.f;
    for (int i = tid; i < 16 * 128; i += 256) {   // zero h_lds
        int m = i >> 7, sg = i & 127;
        uint4 z = {0, 0, 0, 0};
        *(uint4*)&h_lds[m * WSTR + sg * 8] = z;
    }
    {   // xg prefetch for t=0 into buffer 0
        int s0 = dir ? (S_LEN - 1) : 0;
        if (tid < 192) {
            int v0 = tid * 2, m = v0 / 48, c = v0 % 48;
            int gate = c >> 4, j = c & 15;
            unsigned int u = *(const unsigned int*)(xg + (size_t)(m * S_LEN + s0) * 6144 +
                                                   dir * 3072 + gate * 1024 + H0 + j);
            xg_lds[m * 48 + c] = bf2f((unsigned short)(u & 0xffff));
            xg_lds[m * 48 + c + 1] = bf2f((unsigned short)(u >> 16));
        }
    }

    unsigned short* hpp_d = hpp + (size_t)dir * 2 * 8 * 1024;

    for (int t = 0; t < S_LEN; ++t) {
        const int s = dir ? (S_LEN - 1 - t) : t;
        const int buf = t & 1;

        // 1. issue xg prefetch for t+1 (independent of recurrence -> overlaps spin)
        unsigned int nxt = 0;
        int nm = 0, nc = 0;
        const bool has_nxt = (t + 1 < S_LEN) && (tid < 192);
        if (has_nxt) {
            int sn = dir ? (S_LEN - 2 - t) : (t + 1);
            int v0 = tid * 2; nm = v0 / 48; nc = v0 % 48;
            int gate = nc >> 4, j = nc & 15;
            nxt = *(const unsigned int*)(xg + (size_t)(nm * S_LEN + sn) * 6144 +
                                         dir * 3072 + gate * 1024 + H0 + j);
        }
        // 2. wait for h_{t-1} from all wgs of this direction
        if (t > 0) {
            if (tid == 0) {
                const unsigned int tgt = (unsigned int)(NWG_DIR * t);
                while (__hip_atomic_load(&cnt[dir], __ATOMIC_ACQUIRE, __HIP_MEMORY_SCOPE_AGENT) < tgt)
                    __builtin_amdgcn_s_sleep(2);
            }
            __syncthreads();
            // 3. stage h_{t-1} (16 KB) into LDS
            const unsigned short* hsrc = hpp_d + (size_t)((t - 1) & 1) * 8 * 1024;
            for (int i = tid; i < 1024; i += 256) {
                int m = i >> 7, sg = i & 127;
                uint4 vv = *(const uint4*)(hsrc + m * 1024 + sg * 8);
                *(uint4*)&h_lds[m * WSTR + sg * 8] = vv;
            }
        }
        // 4. commit prefetched xg into the other buffer
        if (has_nxt) {
            xg_lds[(buf ^ 1) * 384 + nm * 48 + nc] = bf2f((unsigned short)(nxt & 0xffff));
            xg_lds[(buf ^ 1) * 384 + nm * 48 + nc + 1] = bf2f((unsigned short)(nxt >> 16));
        }
        __syncthreads();
        // 5. hg partials: K split across 4 waves (256 each), 3 gate tiles
        f32x4 pacc[3] = {};
#pragma unroll
        for (int kk = 0; kk < 8; ++kk) {
            const int k0 = (wave * 8 + kk) * 32 + q * 8;
            bf16x8 a = *(const bf16x8*)&h_lds[lm * WSTR + k0];
#pragma unroll
            for (int tl = 0; tl < 3; ++tl) {
                bf16x8 b = *(const bf16x8*)&w_lds[(tl * 16 + lm) * WSTR + k0];
                pacc[tl] = __builtin_amdgcn_mfma_f32_16x16x32_bf16(a, b, pacc[tl], 0, 0, 0);
            }
        }
#pragma unroll
        for (int tl = 0; tl < 3; ++tl)
            *(f32x4*)&red[((wave * 3 + tl) * 64 + lane) * 4] = pacc[tl];
        __syncthreads();
        // 6. gates + state update (threads 0..127 = 8 batch x 16 hidden)
        if (tid < 128) {
            const int m = tid >> 4, hh = tid & 15;
            const int cl = (m >> 2) * 16 + hh, rg = m & 3;
            float rp = 0.f, zp = 0.f, np = 0.f;
#pragma unroll
            for (int wv = 0; wv < 4; ++wv) {
                rp += red[((wv * 3 + 0) * 64 + cl) * 4 + rg];
                zp += red[((wv * 3 + 1) * 64 + cl) * 4 + rg];
                np += red[((wv * 3 + 2) * 64 + cl) * 4 + rg];
            }
            const float* xb = &xg_lds[buf * 384 + m * 48];
            float rr = xb[hh] + rp + bhh_l[hh];
            float zz = xb[16 + hh] + zp + bhh_l[16 + hh];
            float hn_ = np + bhh_l[32 + hh];
            float rgate = 1.f / (1.f + __expf(-rr));
            float zgate = 1.f / (1.f + __expf(-zz));
            float ngate = tanhf(xb[32 + hh] + rgate * hn_);
            float hv = (1.f - zgate) * ngate + zgate * hstate[tid];
            hstate[tid] = hv;
            unsigned short hb = f2bf(hv);
            hpp_d[(size_t)(t & 1) * 8 * 1024 + m * 1024 + H0 + hh] = hb;
            out[(size_t)(m * S_LEN + s) * 2048 + dir * 1024 + H0 + hh] = hb;
        }
        // 7. publish h_t: fence all threads' stores, then one release-add
        __threadfence();
        __syncthreads();
        if (tid == 0)
            __hip_atomic_fetch_add(&cnt[dir], 1u, __ATOMIC_RELEASE, __HIP_MEMORY_SCOPE_AGENT);
    }
}

// ---------------------------------------------------------------------------
extern "C" void kernel_launch(void* const* d_in, const int* in_sizes, int n_in,
                              void* d_out, int out_size, void* d_ws, size_t ws_size,
                              hipStream_t stream) {
    (void)in_sizes; (void)n_in; (void)out_size; (void)ws_size;
    const void* x    = d_in[0];
    const unsigned int* dt = (const unsigned int*)d_in[1];   // gru_norm_w (all ones) = dtype canary
    const void* gnw  = d_in[1];
    const void* wih0 = d_in[2];
    const void* whh0 = d_in[3];
    const void* bih0 = d_in[4];
    const void* bhh0 = d_in[5];
    const void* wih1 = d_in[6];
    const void* whh1 = d_in[7];
    const void* bih1 = d_in[8];
    const void* bhh1 = d_in[9];
    const void* gow  = d_in[10];
    const void* fnw  = d_in[11];
    const void* w1   = d_in[12];
    const void* w2   = d_in[13];
    const void* w3   = d_in[14];

    char* ws = (char*)d_ws;
    size_t o = 0;
    auto alloc = [&](size_t b) { size_t r = o; o += (b + 255) & ~(size_t)255; return r; };
    const size_t oCNT = alloc(256);
    const size_t oHPP = alloc((size_t)2 * 2 * 8 * 1024 * 2);
    const size_t oHN  = alloc((size_t)8192 * 1024 * 2);       // hnorm, later hn
    const size_t oXG  = alloc((size_t)8192 * 6144 * 2);       // xg; later act+g (FFN)
    const size_t oG0  = alloc((size_t)8192 * 2048 * 2);       // gru layer0 out; later x1 (fp32)
    const size_t oG1  = alloc((size_t)8192 * 2048 * 2);       // gru layer1 out

    unsigned int* cnt    = (unsigned int*)(ws + oCNT);
    unsigned short* hpp  = (unsigned short*)(ws + oHPP);
    unsigned short* hnrm = (unsigned short*)(ws + oHN);
    unsigned short* xg   = (unsigned short*)(ws + oXG);
    unsigned short* g0   = (unsigned short*)(ws + oG0);
    unsigned short* g1   = (unsigned short*)(ws + oG1);
    unsigned short* act  = xg;                                 // reuse (xg dead by FFN)
    unsigned short* gbuf = xg + (size_t)8192 * 2816;
    float* x1            = (float*)(ws + oG0);                 // reuse (g0 dead by proj)

    const size_t lds = (size_t)(48 + 16) * WSTR * 2 + (768 + 3072 + 128 + 48) * 4;
    // Allow >64KB dynamic LDS (gfx950 has 160 KiB/CU). Not a stream op; capture-safe.
    (void)hipFuncSetAttribute(reinterpret_cast<const void*>(&gru_recur),
                              hipFuncAttributeMaxDynamicSharedMemorySize, (int)lds);

    hipMemsetAsync(ws + oCNT, 0, 256, stream);
    rmsnorm_k<true><<<8192, 256, 0, stream>>>(x, gnw, hnrm, dt);
    gemm_bt<EPI_NONE, OUT_BF16, true><<<dim3(48, 64), 256, 0, stream>>>(hnrm, wih0, bih0, nullptr, xg, 6144, 1024, dt);
    gru_recur<<<128, 256, lds, stream>>>(xg, whh0, bhh0, g0, hpp, cnt, dt);
    gemm_bt<EPI_NONE, OUT_BF16, true><<<dim3(48, 64), 256, 0, stream>>>(g0, wih1, bih1, nullptr, xg, 6144, 2048, dt);
    gru_recur<<<128, 256, lds, stream>>>(xg, whh1, bhh1, g1, hpp, cnt + 2, dt);
    gemm_bt<EPI_ADD_EXT, OUT_F32, false><<<dim3(8, 64), 256, 0, stream>>>(g1, gow, nullptr, x, x1, 1024, 2048, dt);
    rmsnorm_k<false><<<8192, 256, 0, stream>>>(x1, fnw, hnrm, dt);
    gemm_bt<EPI_SILU, OUT_BF16, false><<<dim3(22, 64), 256, 0, stream>>>(hnrm, w1, nullptr, nullptr, act, 2816, 1024, dt);
    gemm_bt<EPI_MUL_I, OUT_BF16, false><<<dim3(22, 64), 256, 0, stream>>>(hnrm, w3, nullptr, act, gbuf, 2816, 1024, dt);
    gemm_bt<EPI_ADD_F32, OUT_EXT, false><<<dim3(8, 64), 256, 0, stream>>>(gbuf, w2, nullptr, x1, d_out, 1024, 2816, dt);
}

// Round 3
// 10447.002 us; speedup vs baseline: 3.3441x; 3.3441x over previous
//
#include <hip/hip_runtime.h>
#include <stdint.h>

// ---------------------------------------------------------------------------
// BidirectionalGRU: rmsnorm -> 2-layer bidirectional GRU -> out-proj residual
//                   -> rmsnorm -> SwiGLU FFN residual.
// B=8, S=1024, DIM=1024, FFN_HID=2816.
// External dtype (fp32 vs bf16) detected at runtime from gru_norm_w (all-ones):
// first u32 == 0x3F800000 iff fp32. Internal compute/storage is bf16 + fp32 acc.
//
// R3: GRU cross-wg sync rebuilt. R2's cnt-atomicAdd (64-way same-address RMW,
// serialized at the coherent point) + __threadfence (L2 wb/inv per step) cost
// ~16.8 us/step. Now: per-wg flag stores (no RMW), relaxed agent-scope atomic
// h transfer (sc1 bypass, coherent at MALL, no fences), hand-rolled release
// via s_waitcnt vmcnt(0) within wave 0.
// ---------------------------------------------------------------------------

#define S_LEN 1024
#define NWG_DIR 64     // workgroups per GRU direction
#define HPW 16         // hidden units per workgroup
#define WSTR 1032      // LDS row stride (elems) for weight/h tiles (pad 8)

typedef __attribute__((ext_vector_type(8))) __bf16 bf16x8;
typedef __attribute__((ext_vector_type(4))) float f32x4;

__device__ __forceinline__ float bf2f(unsigned short u) {
    union { unsigned int i; float f; } v; v.i = ((unsigned int)u) << 16; return v.f;
}
__device__ __forceinline__ unsigned short f2bf(float f) {
    unsigned int i = __float_as_uint(f);
    unsigned int r = (i + 0x7fffu + ((i >> 16) & 1u)) >> 16;   // RNE
    return (unsigned short)r;
}
__device__ __forceinline__ bool dt_is_f32(const unsigned int* dt) {
    return dt[0] == 0x3F800000u;
}
__device__ __forceinline__ float ld_ext(const void* p, long i, bool f32) {
    return f32 ? ((const float*)p)[i] : bf2f(((const unsigned short*)p)[i]);
}
__device__ __forceinline__ void st8bf(unsigned short* d, float4 a, float4 b) {
    uint4 u;
    u.x = (unsigned)f2bf(a.x) | ((unsigned)f2bf(a.y) << 16);
    u.y = (unsigned)f2bf(a.z) | ((unsigned)f2bf(a.w) << 16);
    u.z = (unsigned)f2bf(b.x) | ((unsigned)f2bf(b.y) << 16);
    u.w = (unsigned)f2bf(b.z) | ((unsigned)f2bf(b.w) << 16);
    *(uint4*)d = u;
}
__device__ __forceinline__ void gload_lds16(const void* g, void* l) {
    __builtin_amdgcn_global_load_lds(
        (const __attribute__((address_space(1))) unsigned int*)g,
        (__attribute__((address_space(3))) unsigned int*)l, 16, 0, 0);
}
__device__ __forceinline__ unsigned int a_ld32(const unsigned int* p) {
    return __hip_atomic_load(p, __ATOMIC_RELAXED, __HIP_MEMORY_SCOPE_AGENT);
}
__device__ __forceinline__ unsigned long long a_ld64(const unsigned long long* p) {
    return __hip_atomic_load(p, __ATOMIC_RELAXED, __HIP_MEMORY_SCOPE_AGENT);
}
__device__ __forceinline__ void a_st32(unsigned int* p, unsigned int v) {
    __hip_atomic_store(p, v, __ATOMIC_RELAXED, __HIP_MEMORY_SCOPE_AGENT);
}

// ---------------------------------------------------------------------------
// RMSNorm over 1024-elem rows. EXT_IN: x is an external input (flag dtype);
// otherwise x is the internal fp32 buffer. Output always internal bf16.
// ---------------------------------------------------------------------------
template <bool EXT_IN>
__global__ __launch_bounds__(256) void rmsnorm_k(const void* __restrict__ xin,
                                                 const void* __restrict__ w,
                                                 unsigned short* __restrict__ outp,
                                                 const unsigned int* __restrict__ dt) {
    const bool f32 = dt_is_f32(dt);
    const long row = blockIdx.x;
    const int tid = threadIdx.x;
    float v[4];
    if (!EXT_IN || f32) {
        const float* x = (const float*)xin + row * 1024 + tid * 4;
        f32x4 f = *(const f32x4*)x;
        v[0] = f[0]; v[1] = f[1]; v[2] = f[2]; v[3] = f[3];
    } else {
        const unsigned short* x = (const unsigned short*)xin + row * 1024 + tid * 4;
        uint2 u = *(const uint2*)x;
        v[0] = bf2f((unsigned short)(u.x & 0xffff)); v[1] = bf2f((unsigned short)(u.x >> 16));
        v[2] = bf2f((unsigned short)(u.y & 0xffff)); v[3] = bf2f((unsigned short)(u.y >> 16));
    }
    float ss = v[0]*v[0] + v[1]*v[1] + v[2]*v[2] + v[3]*v[3];
    for (int off = 32; off > 0; off >>= 1) ss += __shfl_down(ss, off, 64);
    __shared__ float red[4];
    __shared__ float bc;
    if ((tid & 63) == 0) red[tid >> 6] = ss;
    __syncthreads();
    if (tid == 0) bc = rsqrtf((red[0] + red[1] + red[2] + red[3]) * (1.f / 1024.f) + 1e-5f);
    __syncthreads();
    const float sc = bc;
    unsigned short o0 = f2bf(v[0] * sc * ld_ext(w, tid*4+0, f32));
    unsigned short o1 = f2bf(v[1] * sc * ld_ext(w, tid*4+1, f32));
    unsigned short o2 = f2bf(v[2] * sc * ld_ext(w, tid*4+2, f32));
    unsigned short o3 = f2bf(v[3] * sc * ld_ext(w, tid*4+3, f32));
    *(uint2*)(outp + row * 1024 + tid * 4) =
        make_uint2((unsigned int)o0 | ((unsigned int)o1 << 16),
                   (unsigned int)o2 | ((unsigned int)o3 << 16));
}

// ---------------------------------------------------------------------------
// GEMM: C[M,N] = A[M,K] @ W[N,K]^T (+bias) (+epilogue). A internal bf16;
// W/bias external (flag dtype). 128x128 tile, BK=32, 2x2 waves, 16x16x32 MFMA.
// ---------------------------------------------------------------------------
enum { EPI_NONE = 0, EPI_SILU = 1, EPI_MUL_I = 2, EPI_ADD_EXT = 3, EPI_ADD_F32 = 4 };
enum { OUT_BF16 = 0, OUT_F32 = 1, OUT_EXT = 2 };

template <int EPI, int OUTMODE, bool HAS_BIAS>
__global__ __launch_bounds__(256) void gemm_bt(const unsigned short* __restrict__ A,
                                               const void* __restrict__ W,
                                               const void* __restrict__ bias,
                                               const void* __restrict__ aux,
                                               void* __restrict__ Cout, int N, int K,
                                               const unsigned int* __restrict__ dt) {
    __shared__ __align__(16) unsigned short sA[128 * 32];
    __shared__ __align__(16) unsigned short sB[128 * 32];
    const bool f32 = dt_is_f32(dt);
    const int tid = threadIdx.x;
    const int lane = tid & 63;
    const int wave = tid >> 6;
    const int wm = (wave >> 1) * 64, wn = (wave & 1) * 64;
    const int lm = lane & 15, q = lane >> 4;
    const long rowA0 = (long)blockIdx.y * 128;
    const long rowB0 = (long)blockIdx.x * 128;
    const int r0 = tid >> 2, c0 = tid & 3;

    f32x4 acc[4][4] = {};

    for (int kt = 0; kt < K; kt += 32) {
        gload_lds16(A + (rowA0 + r0) * K + kt + c0 * 8, &sA[tid * 8]);
        gload_lds16(A + (rowA0 + r0 + 64) * K + kt + c0 * 8, &sA[(tid + 256) * 8]);
        if (!f32) {
            const unsigned short* Wb = (const unsigned short*)W;
            gload_lds16(Wb + (rowB0 + r0) * K + kt + c0 * 8, &sB[tid * 8]);
            gload_lds16(Wb + (rowB0 + r0 + 64) * K + kt + c0 * 8, &sB[(tid + 256) * 8]);
        } else {
            const float* Wf = (const float*)W;
            const float* p0 = Wf + (rowB0 + r0) * K + kt + c0 * 8;
            const float* p1 = Wf + (rowB0 + r0 + 64) * K + kt + c0 * 8;
            float4 a0 = *(const float4*)p0, a1 = *(const float4*)(p0 + 4);
            float4 b0 = *(const float4*)p1, b1 = *(const float4*)(p1 + 4);
            st8bf(&sB[tid * 8], a0, a1);
            st8bf(&sB[(tid + 256) * 8], b0, b1);
        }
        __syncthreads();
        bf16x8 af[4], bfr[4];
#pragma unroll
        for (int i = 0; i < 4; ++i) af[i] = *(const bf16x8*)&sA[(wm + i * 16 + lm) * 32 + q * 8];
#pragma unroll
        for (int j = 0; j < 4; ++j) bfr[j] = *(const bf16x8*)&sB[(wn + j * 16 + lm) * 32 + q * 8];
#pragma unroll
        for (int i = 0; i < 4; ++i)
#pragma unroll
            for (int j = 0; j < 4; ++j)
                acc[i][j] = __builtin_amdgcn_mfma_f32_16x16x32_bf16(af[i], bfr[j], acc[i][j], 0, 0, 0);
        __syncthreads();
    }

#pragma unroll
    for (int j = 0; j < 4; ++j) {
        const long col = rowB0 + wn + j * 16 + lm;
        float bv = 0.f;
        if (HAS_BIAS) bv = ld_ext(bias, col, f32);
#pragma unroll
        for (int i = 0; i < 4; ++i) {
#pragma unroll
            for (int r = 0; r < 4; ++r) {
                const long row = rowA0 + wm + i * 16 + q * 4 + r;
                const long idx = row * N + col;
                float v = acc[i][j][r] + bv;
                if (EPI == EPI_SILU)    v = v / (1.f + __expf(-v));
                if (EPI == EPI_MUL_I)   v *= bf2f(((const unsigned short*)aux)[idx]);
                if (EPI == EPI_ADD_EXT) v += ld_ext(aux, idx, f32);
                if (EPI == EPI_ADD_F32) v += ((const float*)aux)[idx];
                if (OUTMODE == OUT_F32)       ((float*)Cout)[idx] = v;
                else if (OUTMODE == OUT_BF16) ((unsigned short*)Cout)[idx] = f2bf(v);
                else { if (f32) ((float*)Cout)[idx] = v; else ((unsigned short*)Cout)[idx] = f2bf(v); }
            }
        }
    }
}

// ---------------------------------------------------------------------------
// GRU recurrence (one bidirectional layer). Grid = 128 wgs x 256 thr.
// wg (dir, slot): owns hidden units [slot*16, slot*16+16). w_hh slice (48 rows
// of 1024) LDS-resident for all 1024 steps.
// Per step: wave0 polls 64 per-wg flags (lane i -> flag i, ballot until all
// >= t); all 256 threads gather h_{t-1} (16 KB) via relaxed agent-scope b64
// atomic loads (sc1, MALL-coherent, no fences) into LDS; MFMA K-split across
// 4 waves; gate math on 128 threads (fp32 carried state); wave0 publishes h_t
// via 64 relaxed atomic dword stores + s_waitcnt vmcnt(0) + flag store (hand-
// rolled release, single wave so per-wave vmcnt ordering is sound).
// xg for step t+1 prefetched into registers during step t.
// ---------------------------------------------------------------------------
__global__ __launch_bounds__(256) void gru_recur(const unsigned short* __restrict__ xg,  // [8192][6144]
                                                 const void* __restrict__ whh,           // [2][3072][1024]
                                                 const void* __restrict__ bhh,           // [2][3072]
                                                 unsigned short* __restrict__ out,       // [8192][2048]
                                                 unsigned short* __restrict__ hpp,       // [2][2][8][1024]
                                                 unsigned int* __restrict__ flags,       // [2][64]
                                                 const unsigned int* __restrict__ dt) {
    extern __shared__ char smem[];
    unsigned short* w_lds = (unsigned short*)smem;            // 48*1032
    unsigned short* h_lds = w_lds + 48 * WSTR;                // 16*1032 (rows 8..15 stay zero)
    float* xg_lds = (float*)(h_lds + 16 * WSTR);              // [2][8][48]
    float* red = xg_lds + 768;                                // [4][3][64][4]
    float* hstate = red + 3072;                               // [8][16] fp32 carried state
    float* bhh_l = hstate + 128;                              // [48]
    unsigned short* hpub = (unsigned short*)(bhh_l + 48);     // [128] publish staging

    const bool f32 = dt_is_f32(dt);
    const int tid = threadIdx.x;
    const int lane = tid & 63, wave = tid >> 6;
    const int dir = blockIdx.x >> 6;
    const int slot = blockIdx.x & 63;
    const int H0 = slot * HPW;
    const int lm = lane & 15, q = lane >> 4;
    unsigned int* fl = flags + dir * 64;

    // ---- one-time init ----
    for (int idx = tid; idx < 48 * 128; idx += 256) {
        int row = idx >> 7, seg = idx & 127;
        int gate = row >> 4, j = row & 15;
        size_t grow = (size_t)(dir * 3072 + gate * 1024 + H0 + j);
        if (!f32) {
            uint4 vv = *(const uint4*)((const unsigned short*)whh + grow * 1024 + seg * 8);
            *(uint4*)&w_lds[row * WSTR + seg * 8] = vv;
        } else {
            const float* wf = (const float*)whh + grow * 1024 + seg * 8;
            float4 a = *(const float4*)wf, b = *(const float4*)(wf + 4);
            st8bf(&w_lds[row * WSTR + seg * 8], a, b);
        }
    }
    if (tid < 48) {
        int gate = tid >> 4, j = tid & 15;
        bhh_l[tid] = ld_ext(bhh, dir * 3072 + gate * 1024 + H0 + j, f32);
    }
    if (tid < 128) hstate[tid] = 0.f;
    for (int i = tid; i < 16 * 128; i += 256) {   // zero h_lds
        int m = i >> 7, sg = i & 127;
        uint4 z = {0, 0, 0, 0};
        *(uint4*)&h_lds[m * WSTR + sg * 8] = z;
    }
    {   // xg prefetch for t=0 into buffer 0
        int s0 = dir ? (S_LEN - 1) : 0;
        if (tid < 192) {
            int v0 = tid * 2, m = v0 / 48, c = v0 % 48;
            int gate = c >> 4, j = c & 15;
            unsigned int u = *(const unsigned int*)(xg + (size_t)(m * S_LEN + s0) * 6144 +
                                                   dir * 3072 + gate * 1024 + H0 + j);
            xg_lds[m * 48 + c] = bf2f((unsigned short)(u & 0xffff));
            xg_lds[m * 48 + c + 1] = bf2f((unsigned short)(u >> 16));
        }
    }

    unsigned short* hpp_d = hpp + (size_t)dir * 2 * 8 * 1024;
    unsigned int* hpp_u32 = (unsigned int*)hpp_d;              // [2][8][512]
    const unsigned long long* hpp_u64 = (const unsigned long long*)hpp_d;  // [2][8][256]

    for (int t = 0; t < S_LEN; ++t) {
        const int s = dir ? (S_LEN - 1 - t) : t;
        const int buf = t & 1;

        // 1. issue xg prefetch for t+1 (independent of recurrence -> overlaps spin)
        unsigned int nxt = 0;
        int nm = 0, nc = 0;
        const bool has_nxt = (t + 1 < S_LEN) && (tid < 192);
        if (has_nxt) {
            int sn = dir ? (S_LEN - 2 - t) : (t + 1);
            int v0 = tid * 2; nm = v0 / 48; nc = v0 % 48;
            int gate = nc >> 4, j = nc & 15;
            nxt = *(const unsigned int*)(xg + (size_t)(nm * S_LEN + sn) * 6144 +
                                         dir * 3072 + gate * 1024 + H0 + j);
        }
        // 2. wait for h_{t-1}: wave0 lane i polls wg i's flag; ballot until all >= t
        if (t > 0) {
            if (wave == 0) {
                unsigned int f;
                do {
                    f = a_ld32(&fl[lane]);
                } while (__ballot(f < (unsigned int)t) != 0ULL);
            }
            __syncthreads();
            // 3. gather h_{t-1} (16 KB) via relaxed b64 atomics -> LDS
            const unsigned long long* src = hpp_u64 + (size_t)((t - 1) & 1) * 2048;
#pragma unroll
            for (int i = 0; i < 8; ++i) {
                int idx = tid + i * 256;
                int m = idx >> 8, qw = idx & 255;
                unsigned long long v = a_ld64(src + m * 256 + qw);
                *(unsigned long long*)&h_lds[m * WSTR + qw * 4] = v;
            }
        }
        // 4. commit prefetched xg into the other buffer
        if (has_nxt) {
            xg_lds[(buf ^ 1) * 384 + nm * 48 + nc] = bf2f((unsigned short)(nxt & 0xffff));
            xg_lds[(buf ^ 1) * 384 + nm * 48 + nc + 1] = bf2f((unsigned short)(nxt >> 16));
        }
        __syncthreads();
        // 5. hg partials: K split across 4 waves (256 each), 3 gate tiles
        f32x4 pacc[3] = {};
#pragma unroll
        for (int kk = 0; kk < 8; ++kk) {
            const int k0 = (wave * 8 + kk) * 32 + q * 8;
            bf16x8 a = *(const bf16x8*)&h_lds[lm * WSTR + k0];
#pragma unroll
            for (int tl = 0; tl < 3; ++tl) {
                bf16x8 b = *(const bf16x8*)&w_lds[(tl * 16 + lm) * WSTR + k0];
                pacc[tl] = __builtin_amdgcn_mfma_f32_16x16x32_bf16(a, b, pacc[tl], 0, 0, 0);
            }
        }
#pragma unroll
        for (int tl = 0; tl < 3; ++tl)
            *(f32x4*)&red[((wave * 3 + tl) * 64 + lane) * 4] = pacc[tl];
        __syncthreads();
        // 6. gates + state update (threads 0..127 = 8 batch x 16 hidden)
        if (tid < 128) {
            const int m = tid >> 4, hh = tid & 15;
            const int cl = (m >> 2) * 16 + hh, rg = m & 3;
            float rp = 0.f, zp = 0.f, np = 0.f;
#pragma unroll
            for (int wv = 0; wv < 4; ++wv) {
                rp += red[((wv * 3 + 0) * 64 + cl) * 4 + rg];
                zp += red[((wv * 3 + 1) * 64 + cl) * 4 + rg];
                np += red[((wv * 3 + 2) * 64 + cl) * 4 + rg];
            }
            const float* xb = &xg_lds[buf * 384 + m * 48];
            float rr = xb[hh] + rp + bhh_l[hh];
            float zz = xb[16 + hh] + zp + bhh_l[16 + hh];
            float hn_ = np + bhh_l[32 + hh];
            float rgate = 1.f / (1.f + __expf(-rr));
            float zgate = 1.f / (1.f + __expf(-zz));
            float ngate = tanhf(xb[32 + hh] + rgate * hn_);
            float hv = (1.f - zgate) * ngate + zgate * hstate[tid];
            hstate[tid] = hv;
            unsigned short hb = f2bf(hv);
            hpub[tid] = hb;
            out[(size_t)(m * S_LEN + s) * 2048 + dir * 1024 + H0 + hh] = hb;
        }
        __syncthreads();
        // 7. publish h_t (wave 0 only): 64 relaxed dword stores, wait store-ack
        //    at coherent point, then flag store. Hand-rolled release.
        if (wave == 0) {
            unsigned int hw = *(const unsigned int*)&hpub[lane * 2];
            int m = lane >> 3, j = lane & 7;
            a_st32(hpp_u32 + ((size_t)buf * 8 + m) * 512 + (H0 >> 1) + j, hw);
            asm volatile("s_waitcnt vmcnt(0)" ::: "memory");
            if (lane == 0) a_st32(&fl[slot], (unsigned int)(t + 1));
        }
    }
}

// ---------------------------------------------------------------------------
extern "C" void kernel_launch(void* const* d_in, const int* in_sizes, int n_in,
                              void* d_out, int out_size, void* d_ws, size_t ws_size,
                              hipStream_t stream) {
    (void)in_sizes; (void)n_in; (void)out_size; (void)ws_size;
    const void* x    = d_in[0];
    const unsigned int* dt = (const unsigned int*)d_in[1];   // gru_norm_w (all ones) = dtype canary
    const void* gnw  = d_in[1];
    const void* wih0 = d_in[2];
    const void* whh0 = d_in[3];
    const void* bih0 = d_in[4];
    const void* bhh0 = d_in[5];
    const void* wih1 = d_in[6];
    const void* whh1 = d_in[7];
    const void* bih1 = d_in[8];
    const void* bhh1 = d_in[9];
    const void* gow  = d_in[10];
    const void* fnw  = d_in[11];
    const void* w1   = d_in[12];
    const void* w2   = d_in[13];
    const void* w3   = d_in[14];

    char* ws = (char*)d_ws;
    size_t o = 0;
    auto alloc = [&](size_t b) { size_t r = o; o += (b + 255) & ~(size_t)255; return r; };
    const size_t oFLG = alloc(2 * 2 * 64 * 4);                // flags: [layer][dir][64]
    const size_t oHPP = alloc((size_t)2 * 2 * 8 * 1024 * 2);
    const size_t oHN  = alloc((size_t)8192 * 1024 * 2);       // hnorm, later hn
    const size_t oXG  = alloc((size_t)8192 * 6144 * 2);       // xg; later act+g (FFN)
    const size_t oG0  = alloc((size_t)8192 * 2048 * 2);       // gru layer0 out; later x1 (fp32)
    const size_t oG1  = alloc((size_t)8192 * 2048 * 2);       // gru layer1 out

    unsigned int* flg    = (unsigned int*)(ws + oFLG);
    unsigned short* hpp  = (unsigned short*)(ws + oHPP);
    unsigned short* hnrm = (unsigned short*)(ws + oHN);
    unsigned short* xg   = (unsigned short*)(ws + oXG);
    unsigned short* g0   = (unsigned short*)(ws + oG0);
    unsigned short* g1   = (unsigned short*)(ws + oG1);
    unsigned short* act  = xg;                                 // reuse (xg dead by FFN)
    unsigned short* gbuf = xg + (size_t)8192 * 2816;
    float* x1            = (float*)(ws + oG0);                 // reuse (g0 dead by proj)

    const size_t lds = (size_t)(48 + 16) * WSTR * 2 + (768 + 3072 + 128 + 48) * 4 + 256;
    // Allow >64KB dynamic LDS (gfx950 has 160 KiB/CU). Not a stream op; capture-safe.
    (void)hipFuncSetAttribute(reinterpret_cast<const void*>(&gru_recur),
                              hipFuncAttributeMaxDynamicSharedMemorySize, (int)lds);

    hipMemsetAsync(ws + oFLG, 0, 2 * 2 * 64 * 4, stream);
    rmsnorm_k<true><<<8192, 256, 0, stream>>>(x, gnw, hnrm, dt);
    gemm_bt<EPI_NONE, OUT_BF16, true><<<dim3(48, 64), 256, 0, stream>>>(hnrm, wih0, bih0, nullptr, xg, 6144, 1024, dt);
    gru_recur<<<128, 256, lds, stream>>>(xg, whh0, bhh0, g0, hpp, flg, dt);
    gemm_bt<EPI_NONE, OUT_BF16, true><<<dim3(48, 64), 256, 0, stream>>>(g0, wih1, bih1, nullptr, xg, 6144, 2048, dt);
    gru_recur<<<128, 256, lds, stream>>>(xg, whh1, bhh1, g1, hpp, flg + 128, dt);
    gemm_bt<EPI_ADD_EXT, OUT_F32, false><<<dim3(8, 64), 256, 0, stream>>>(g1, gow, nullptr, x, x1, 1024, 2048, dt);
    rmsnorm_k<false><<<8192, 256, 0, stream>>>(x1, fnw, hnrm, dt);
    gemm_bt<EPI_SILU, OUT_BF16, false><<<dim3(22, 64), 256, 0, stream>>>(hnrm, w1, nullptr, nullptr, act, 2816, 1024, dt);
    gemm_bt<EPI_MUL_I, OUT_BF16, false><<<dim3(22, 64), 256, 0, stream>>>(hnrm, w3, nullptr, act, gbuf, 2816, 1024, dt);
    gemm_bt<EPI_ADD_F32, OUT_EXT, false><<<dim3(8, 64), 256, 0, stream>>>(gbuf, w2, nullptr, x1, d_out, 1024, 2816, dt);
}